// Round 5
// baseline (4882.754 us; speedup 1.0000x reference)
//
#include <hip/hip_runtime.h>
#include <math.h>

// Problem dims (fixed)
#define NOTES 78
#define IN_DIM 80
#define T_HID 64
#define N_HID 2
#define BATCH 64
#define TLEN 128
#define NSEQ (BATCH * NOTES)          // 4992 time-LSTM sequences
#define NBT  (BATCH * TLEN)           // 8192 note-LSTM sequences
#define SB   8                        // sequences per block in time-LSTM

__device__ __forceinline__ float sigf(float x) { return 1.0f / (1.0f + expf(-x)); }
__device__ __forceinline__ float rdl(float v, int k) {
    return __int_as_float(__builtin_amdgcn_readlane(__float_as_int(v), k));
}

// ---------------------------------------------------------------------------
// Fused time-LSTM + note-input projection.  R5:
//   - amdgpu_waves_per_eu(2,2): pin scheduler occupancy target at 2 waves/EU
//     (VGPR budget 256). R1/R3/R4 all failed because the default target
//     (4+ waves -> <=128 VGPR) makes the allocator rematerialize loop-invariant
//     weight loads into the K-loop -> L2-bound (~23 GB/dispatch weight re-reads).
//   - uniform role: 1 gate/thread (g = tid), full K=144 row in 144 VGPRs,
//     SB=8 accumulators -> readlane broadcast amortized 8x (1.125 inst/MAC).
//   - activations via v_readlane from per-lane regs (R2 lesson: LDS data path
//     charges 64 lanes x 4B even for same-address broadcast).
// ---------------------------------------------------------------------------
__global__ __launch_bounds__(256) __attribute__((amdgpu_waves_per_eu(2, 2)))
void time_lstm_fused(const float* __restrict__ x,
                     const float* __restrict__ w_ih,
                     const float* __restrict__ w_hh,
                     const float* __restrict__ b_ih,
                     const float* __restrict__ b_hh,
                     const float* __restrict__ w_ih_n,
                     const float* __restrict__ b_ih_n,
                     const float* __restrict__ b_hh_n,
                     float* __restrict__ gxn) {
    __shared__ float hbuf[SB][T_HID];    // 2 KB   h_{t-1}
    __shared__ float G[SB][256];         // 8 KB   ACTIVATED gates

    const int tid  = threadIdx.x;
    const int s0   = blockIdx.x * SB;
    const int g    = tid;                // gate row 0..255
    const int lane = tid & 63;
    const int gtype = tid >> 6;          // wave id == gate type: 0=i 1=f 2=g 3=o

    // ---- full weight row in registers: 20 + 16 float4 = 144 VGPR ----
    float4 wih[20], whh[16];
    {
        const float4* p = (const float4*)(w_ih + (size_t)g * IN_DIM);
#pragma unroll
        for (int j = 0; j < 20; j++) wih[j] = p[j];
        const float4* q = (const float4*)(w_hh + (size_t)g * T_HID);
#pragma unroll
        for (int j = 0; j < 16; j++) whh[j] = q[j];
    }
    const float bias = b_ih[g] + b_hh[g];

    // x row bases (block-uniform -> SGPRs)
    const float* xr[SB];
#pragma unroll
    for (int s = 0; s < SB; s++) xr[s] = x + (size_t)(s0 + s) * TLEN * IN_DIM;

    // ---- gxn identity: 8 seqs x 8 outs x 4-way k-split = 256 threads ----
    const int su2 = tid >> 5;            // seq 0..7
    const int nj  = (tid >> 2) & 7;      // output gate row 0..7
    const int nk  = tid & 3;             // k-split 0..3 (16 h-elements each)
    float wn[16];
#pragma unroll
    for (int i = 0; i < 16; i++) wn[i] = w_ih_n[nj * 64 + nk * 16 + i];
    const float nbias = b_ih_n[nj] + b_hh_n[nj];
    const int sglb = s0 + su2;
    const int nb = sglb / NOTES, nn = sglb % NOTES;
    float* gout = gxn + ((size_t)nn * NBT + (size_t)nb * TLEN) * 8 + nj;

    // phase-B identity: thread handles (sA, u) and (sB, u)
    const int u  = lane;
    const int sA = tid >> 6;             // 0..3
    const int sB = sA + 4;
    float c0 = 0.0f, c1 = 0.0f;

    // init: zero hbuf, load xa for t=0
    ((float*)hbuf)[tid] = 0.0f;
    ((float*)hbuf)[tid + 256] = 0.0f;
    float xa[SB];                        // x_t[lane] per seq
#pragma unroll
    for (int s = 0; s < SB; s++) xa[s] = xr[s][lane];
    __syncthreads();

    for (int t = 0; t < TLEN; t++) {
        // per-lane operand loads for this step (issued early, consumed late)
        float xb[SB], hv[SB], xna[SB];
#pragma unroll
        for (int s = 0; s < SB; s++) xb[s] = xr[s][t * IN_DIM + 64 + (lane & 15)];
#pragma unroll
        for (int s = 0; s < SB; s++) hv[s] = hbuf[s][lane];   // stride-1, conflict-free
        const bool pf = (t + 1 < TLEN);
        if (pf) {
#pragma unroll
            for (int s = 0; s < SB; s++) xna[s] = xr[s][(t + 1) * IN_DIM + lane];
        }

        // ---- gxn for h_{t-1} (hbuf) ----
        if (t > 0) {
            float p = 0.0f;
#pragma unroll
            for (int i = 0; i < 16; i++)
                p = fmaf(wn[i], hbuf[su2][nk * 16 + i], p);
            p += __shfl_xor(p, 1);
            p += __shfl_xor(p, 2);
            if (nk == 0) gout[(size_t)(t - 1) * 8] = p + nbias;
        }

        // ---- phase A: full gate pre-activation for 8 seqs ----
        float acc[SB];
#pragma unroll
        for (int s = 0; s < SB; s++) acc[s] = bias;
#pragma unroll
        for (int k4 = 0; k4 < 16; k4++) {          // x k=0..63
            const float4 wv = wih[k4];
#pragma unroll
            for (int s = 0; s < SB; s++) {
                const float r0 = rdl(xa[s], 4 * k4 + 0);
                const float r1 = rdl(xa[s], 4 * k4 + 1);
                const float r2 = rdl(xa[s], 4 * k4 + 2);
                const float r3 = rdl(xa[s], 4 * k4 + 3);
                acc[s] = fmaf(wv.w, r3, fmaf(wv.z, r2,
                         fmaf(wv.y, r1, fmaf(wv.x, r0, acc[s]))));
            }
        }
#pragma unroll
        for (int k4 = 16; k4 < 20; k4++) {         // x k=64..79 (lanes 0..15 of xb)
            const float4 wv = wih[k4];
#pragma unroll
            for (int s = 0; s < SB; s++) {
                const float r0 = rdl(xb[s], 4 * k4 - 64);
                const float r1 = rdl(xb[s], 4 * k4 - 63);
                const float r2 = rdl(xb[s], 4 * k4 - 62);
                const float r3 = rdl(xb[s], 4 * k4 - 61);
                acc[s] = fmaf(wv.w, r3, fmaf(wv.z, r2,
                         fmaf(wv.y, r1, fmaf(wv.x, r0, acc[s]))));
            }
        }
#pragma unroll
        for (int k4 = 0; k4 < 16; k4++) {          // h k=0..63
            const float4 wv = whh[k4];
#pragma unroll
            for (int s = 0; s < SB; s++) {
                const float r0 = rdl(hv[s], 4 * k4 + 0);
                const float r1 = rdl(hv[s], 4 * k4 + 1);
                const float r2 = rdl(hv[s], 4 * k4 + 2);
                const float r3 = rdl(hv[s], 4 * k4 + 3);
                acc[s] = fmaf(wv.w, r3, fmaf(wv.z, r2,
                         fmaf(wv.y, r1, fmaf(wv.x, r0, acc[s]))));
            }
        }

        // activation (wave-uniform branch) + stage activated gates
#pragma unroll
        for (int s = 0; s < SB; s++) {
            const float v = (gtype == 2) ? tanhf(acc[s]) : sigf(acc[s]);
            G[s][g] = v;
        }
        __syncthreads();   // barrier 1: G complete, hbuf reads done

        // ---- phase B: state update, 2 (seq,unit) pairs per thread ----
        {
            const float iv = G[sA][u], fv = G[sA][64 + u];
            const float gv = G[sA][128 + u], ov = G[sA][192 + u];
            c0 = fv * c0 + iv * gv;
            hbuf[sA][u] = ov * tanhf(c0);
        }
        {
            const float iv = G[sB][u], fv = G[sB][64 + u];
            const float gv = G[sB][128 + u], ov = G[sB][192 + u];
            c1 = fv * c1 + iv * gv;
            hbuf[sB][u] = ov * tanhf(c1);
        }
        if (pf) {
#pragma unroll
            for (int s = 0; s < SB; s++) xa[s] = xna[s];
        }
        __syncthreads();   // barrier 2: hbuf = h_t ready
    }

    // epilogue: gxn for h_127
    {
        float p = 0.0f;
#pragma unroll
        for (int i = 0; i < 16; i++)
            p = fmaf(wn[i], hbuf[su2][nk * 16 + i], p);
        p += __shfl_xor(p, 1);
        p += __shfl_xor(p, 2);
        if (nk == 0) gout[(size_t)(TLEN - 1) * 8] = p + nbias;
    }
}

// ---------------------------------------------------------------------------
// Note-LSTM scan over 78 notes, fresh zero state per (b,t).
// One thread per bt; outputs buffered in registers, stored as float4 at end.
// ---------------------------------------------------------------------------
__global__ __launch_bounds__(64)
void note_scan_kernel(const float* __restrict__ gxn,
                      const float* __restrict__ w_hh_n,
                      float* __restrict__ out) {
    const int bt = blockIdx.x * 64 + threadIdx.x;         // < 8192
    float wh[16];
#pragma unroll
    for (int i = 0; i < 16; i++) wh[i] = w_hh_n[i];       // [8][2] row-major
    float h0 = 0.f, h1 = 0.f, c0 = 0.f, c1 = 0.f;

    const float4* gp = (const float4*)gxn;                // f4 index = (n*NBT+bt)*2
    float res[2 * NOTES];                                 // output row buffer

    size_t idx = (size_t)bt * 2;
    float4 ga = gp[idx], gb = gp[idx + 1];
    for (int n = 0; n < NOTES; n++) {
        float4 na, nb2;
        if (n + 1 < NOTES) {
            const size_t nidx = ((size_t)(n + 1) * NBT + bt) * 2;
            na  = gp[nidx];
            nb2 = gp[nidx + 1];
        }
        const float i0 = ga.x + wh[0]  * h0 + wh[1]  * h1;
        const float i1 = ga.y + wh[2]  * h0 + wh[3]  * h1;
        const float f0 = ga.z + wh[4]  * h0 + wh[5]  * h1;
        const float f1 = ga.w + wh[6]  * h0 + wh[7]  * h1;
        const float g0 = gb.x + wh[8]  * h0 + wh[9]  * h1;
        const float g1 = gb.y + wh[10] * h0 + wh[11] * h1;
        const float o0 = gb.z + wh[12] * h0 + wh[13] * h1;
        const float o1 = gb.w + wh[14] * h0 + wh[15] * h1;
        c0 = sigf(f0) * c0 + sigf(i0) * tanhf(g0);
        c1 = sigf(f1) * c1 + sigf(i1) * tanhf(g1);
        h0 = sigf(o0) * tanhf(c0);
        h1 = sigf(o1) * tanhf(c1);
        res[n * 2 + 0] = (h0 > 0.5f) ? 1.0f : 0.0f;
        res[n * 2 + 1] = (h1 > 0.5f) ? 1.0f : 0.0f;
        ga = na; gb = nb2;
    }
    float4* op = (float4*)(out + (size_t)bt * (NOTES * N_HID));
#pragma unroll
    for (int j = 0; j < (2 * NOTES) / 4; j++) {
        op[j] = make_float4(res[4 * j], res[4 * j + 1], res[4 * j + 2], res[4 * j + 3]);
    }
}

// ---------------------------------------------------------------------------
extern "C" void kernel_launch(void* const* d_in, const int* in_sizes, int n_in,
                              void* d_out, int out_size, void* d_ws, size_t ws_size,
                              hipStream_t stream) {
    const float* x      = (const float*)d_in[0];  // (64,78,128,80)
    const float* w_ih_t = (const float*)d_in[1];  // (256,80)
    const float* w_hh_t = (const float*)d_in[2];  // (256,64)
    const float* b_ih_t = (const float*)d_in[3];  // (256)
    const float* b_hh_t = (const float*)d_in[4];  // (256)
    const float* w_ih_n = (const float*)d_in[5];  // (8,64)
    const float* w_hh_n = (const float*)d_in[6];  // (8,2)
    const float* b_ih_n = (const float*)d_in[7];  // (8)
    const float* b_hh_n = (const float*)d_in[8];  // (8)
    float* out = (float*)d_out;                   // (64,128,156)

    // workspace: gxn = [78][8192][8] fp32 = 20.4 MB
    float* gxn = (float*)d_ws;

    time_lstm_fused<<<NSEQ / SB, 256, 0, stream>>>(
        x, w_ih_t, w_hh_t, b_ih_t, b_hh_t, w_ih_n, b_ih_n, b_hh_n, gxn);
    note_scan_kernel<<<NBT / 64, 64, 0, stream>>>(gxn, w_hh_n, out);
}